// Round 2
// baseline (1089.603 us; speedup 1.0000x reference)
//
#include <hip/hip_runtime.h>
#include <hip/hip_bf16.h>
#include <cstdint>
#include <cstddef>

#define NUM_NODES 500000
#define DIM 128
#define BATCH 131072
#define GRU_BLOCKS (BATCH / 32)                    // 4096
#define COPY_BLOCKS ((NUM_NODES * 32 + 511) / 512) // 31250

typedef __attribute__((ext_vector_type(8))) short short8;
typedef __attribute__((ext_vector_type(4))) short short4_t;
typedef __attribute__((ext_vector_type(4))) float f32x4;

static __device__ __forceinline__ short f2bf(float f) {
    unsigned u = __builtin_bit_cast(unsigned, f);
    u += 0x7fffu + ((u >> 16) & 1u);   // round-to-nearest-even
    return (short)(u >> 16);
}

// ---------------------------------------------------------------- init ----
__global__ void k_init(unsigned char* __restrict__ mask,
                       const float* __restrict__ Wih,
                       const float* __restrict__ Whh,
                       short* __restrict__ WbIH,
                       short* __restrict__ WbHH,
                       int do_mask) {
    int i = blockIdx.x * blockDim.x + threadIdx.x;
    if (do_mask && i < NUM_NODES) mask[i] = 0;
    if (i < 3 * DIM * DIM) {
        WbIH[i] = f2bf(Wih[i]);
        WbHH[i] = f2bf(Whh[i]);
    }
}

__global__ void k_scatter(unsigned char* __restrict__ mask, const int* __restrict__ idx) {
    int i = blockIdx.x * blockDim.x + threadIdx.x;
    if (i < BATCH) mask[idx[i]] = 1;
}

// ------------------------------------------------------------ gru body ----
__device__ __forceinline__ void gru_body(
        int g, int t, char* smem,
        const float* __restrict__ hidden, const float* __restrict__ variance,
        const int* __restrict__ idx, const float* __restrict__ xg,
        const short* __restrict__ WbIH, const short* __restrict__ WbHH,
        const float* __restrict__ b_ih, const float* __restrict__ b_hh,
        float* __restrict__ out0, float* __restrict__ out1) {
    short (*Xb)[136] = (short(*)[136])smem;             // bf16 x tile
    short (*Hb)[136] = (short(*)[136])(smem + 8704);    // bf16 h tile
    float (*Hf)[132] = (float(*)[132])(smem + 17408);   // f32 h tile
    float (*Hn)[132] = (float(*)[132])smem;             // h_new, OVERLAYS Xb+Hb
    int*   nodeS     = (int*)(smem + 34304);

    const int rb = g * 32;
    if (t < 32) nodeS[t] = idx[rb + t];
    __syncthreads();

    // ---- stage x (f32->bf16) and gathered h (f32->bf16 + f32) ----
    for (int j = t; j < 1024; j += 512) {               // 1024 float4 chunks
        int row = j >> 5, c4 = j & 31;
        int node = nodeS[row];
        f32x4 xv = *(const f32x4*)(xg + (size_t)(rb + row) * DIM + c4 * 4);
        f32x4 hv = *(const f32x4*)(hidden + (size_t)node * DIM + c4 * 4);
        short4_t xs, hs;
        xs.x = f2bf(xv.x); xs.y = f2bf(xv.y); xs.z = f2bf(xv.z); xs.w = f2bf(xv.w);
        hs.x = f2bf(hv.x); hs.y = f2bf(hv.y); hs.z = f2bf(hv.z); hs.w = f2bf(hv.w);
        *(short4_t*)&Xb[row][c4 * 4] = xs;
        *(short4_t*)&Hb[row][c4 * 4] = hs;
        *(f32x4*)&Hf[row][c4 * 4]    = hv;
    }
    __syncthreads();

    const int w  = t >> 6;       // wave id 0..7 -> output dims 16w..16w+15
    const int l  = t & 63;
    const int c  = l & 15;
    const int gq = l >> 4;

    f32x4 acc[2][3][2] = {};     // [m-tile][gate third][0=x@Wih 1=h@Whh]

    #pragma unroll
    for (int ks = 0; ks < 4; ++ks) {
        const int k0 = ks * 32 + gq * 8;
        short8 a[2][2];
        a[0][0] = *(const short8*)&Xb[c][k0];
        a[1][0] = *(const short8*)&Xb[16 + c][k0];
        a[0][1] = *(const short8*)&Hb[c][k0];
        a[1][1] = *(const short8*)&Hb[16 + c][k0];
        #pragma unroll
        for (int th = 0; th < 3; ++th) {
            const int o = w * 16 + th * 128 + c;        // gate output row of W
            const short8 bi = *(const short8*)(WbIH + (size_t)o * DIM + k0);
            const short8 bh = *(const short8*)(WbHH + (size_t)o * DIM + k0);
            #pragma unroll
            for (int mt = 0; mt < 2; ++mt) {
                acc[mt][th][0] = __builtin_amdgcn_mfma_f32_16x16x32_bf16(a[mt][0], bi, acc[mt][th][0], 0, 0, 0);
                acc[mt][th][1] = __builtin_amdgcn_mfma_f32_16x16x32_bf16(a[mt][1], bh, acc[mt][th][1], 0, 0, 0);
            }
        }
    }

    __syncthreads();   // Xb/Hb dead; safe to overlay with Hn

    // ---- per-lane gate math; lane holds (m = mt*16 + gq*4 + r, d = 16w+c) ----
    const int d = w * 16 + c;
    const float bs_r = b_ih[d]       + b_hh[d];
    const float bs_z = b_ih[d + 128] + b_hh[d + 128];
    const float bi_n = b_ih[d + 256];
    const float bh_n = b_hh[d + 256];

    #pragma unroll
    for (int mt = 0; mt < 2; ++mt) {
        #pragma unroll
        for (int r = 0; r < 4; ++r) {
            const int m = mt * 16 + gq * 4 + r;
            float s_r  = acc[mt][0][0][r] + acc[mt][0][1][r] + bs_r;
            float s_z  = acc[mt][1][0][r] + acc[mt][1][1][r] + bs_z;
            float gi_n = acc[mt][2][0][r] + bi_n;
            float gh_n = acc[mt][2][1][r] + bh_n;
            float rg = 1.f / (1.f + __expf(-s_r));
            float zg = 1.f / (1.f + __expf(-s_z));
            float aa = gi_n + rg * gh_n;
            float n  = 1.f - 2.f / (__expf(2.f * aa) + 1.f);   // tanh, inf-safe
            float h  = Hf[m][d];
            Hn[m][d] = (1.f - zg) * n + zg * h;
        }
    }
    __syncthreads();

    // ---- vectorized epilogue: coalesced variance read + both outputs ----
    for (int j = t; j < 1024; j += 512) {
        int row = j >> 5, c4 = j & 31;
        int node = nodeS[row];
        size_t off = (size_t)node * DIM + c4 * 4;
        f32x4 hn = *(f32x4*)&Hn[row][c4 * 4];
        f32x4 h  = *(f32x4*)&Hf[row][c4 * 4];
        f32x4 vv = *(const f32x4*)(variance + off);
        f32x4 var;
        var.x = 0.9f * vv.x + 0.1f * (hn.x - h.x) * (hn.x - h.x);
        var.y = 0.9f * vv.y + 0.1f * (hn.y - h.y) * (hn.y - h.y);
        var.z = 0.9f * vv.z + 0.1f * (hn.z - h.z) * (hn.z - h.z);
        var.w = 0.9f * vv.w + 0.1f * (hn.w - h.w) * (hn.w - h.w);
        *(f32x4*)(out0 + off) = hn;
        *(f32x4*)(out1 + off) = var;
    }
}

// ----------------------------------------------------------- copy body ----
__device__ __forceinline__ void copy_body(
        int cb, int t,
        const float* __restrict__ hidden, const float* __restrict__ variance,
        const unsigned char* __restrict__ mask,   // null -> copy all
        float* __restrict__ out0, float* __restrict__ out1) {
    int gid = cb * 512 + t;
    int row = gid >> 5;
    int c4  = gid & 31;
    if (row >= NUM_NODES) return;
    if (mask && mask[row]) return;                // gru writes this row
    size_t off = (size_t)row * DIM + c4 * 4;
    f32x4 a = __builtin_nontemporal_load((const f32x4*)(hidden + off));
    f32x4 b = __builtin_nontemporal_load((const f32x4*)(variance + off));
    __builtin_nontemporal_store(a, (f32x4*)(out0 + off));
    __builtin_nontemporal_store(b, (f32x4*)(out1 + off));
}

// ------------------------------------------------------------- fused ------
// mode 0: fused (gru blocks interleaved every 8th block, copy for the rest)
// mode 1: copy-all only        mode 2: gru only
__global__ void __launch_bounds__(512, 4)
k_main(const float* __restrict__ hidden, const float* __restrict__ variance,
       const int* __restrict__ idx, const float* __restrict__ xg,
       const short* __restrict__ WbIH, const short* __restrict__ WbHH,
       const float* __restrict__ b_ih, const float* __restrict__ b_hh,
       const unsigned char* __restrict__ mask,
       float* __restrict__ out0, float* __restrict__ out1, int mode) {
    __shared__ __align__(16) char smem[34432];
    const int b = blockIdx.x;
    const int t = threadIdx.x;
    if (mode == 1) { copy_body(b, t, hidden, variance, nullptr, out0, out1); return; }
    if (mode == 2) {
        gru_body(b, t, smem, hidden, variance, idx, xg, WbIH, WbHH, b_ih, b_hh, out0, out1);
        return;
    }
    const bool isGru = ((b & 7) == 0) && ((b >> 3) < GRU_BLOCKS);
    if (isGru) {
        gru_body(b >> 3, t, smem, hidden, variance, idx, xg, WbIH, WbHH, b_ih, b_hh, out0, out1);
    } else {
        int nGruBefore = (b >> 3) < GRU_BLOCKS ? (b >> 3) + 1 : GRU_BLOCKS;
        copy_body(b - nGruBefore, t, hidden, variance, mask, out0, out1);
    }
}

// -------------------------------------------------------------- launch ----
extern "C" void kernel_launch(void* const* d_in, const int* in_sizes, int n_in,
                              void* d_out, int out_size, void* d_ws, size_t ws_size,
                              hipStream_t stream) {
    const float* hidden   = (const float*)d_in[0];
    const float* variance = (const float*)d_in[1];
    const int*   idx      = (const int*)d_in[2];
    const float* x        = (const float*)d_in[3];
    const float* Wih      = (const float*)d_in[4];
    const float* Whh      = (const float*)d_in[5];
    const float* bih      = (const float*)d_in[6];
    const float* bhh      = (const float*)d_in[7];
    float* out0 = (float*)d_out;
    float* out1 = out0 + (size_t)NUM_NODES * DIM;

    const size_t maskBytes = (size_t)NUM_NODES;               // 1 byte per node
    const size_t wBytes    = (size_t)3 * DIM * DIM * 2;       // per matrix (bf16)
    const bool   have_mask = ws_size >= maskBytes + 2 * wBytes;

    unsigned char* mask = have_mask ? (unsigned char*)d_ws : nullptr;
    short* WbIH = have_mask ? (short*)((char*)d_ws + ((maskBytes + 15) & ~size_t(15)))
                            : (short*)d_ws;
    short* WbHH = WbIH + 3 * DIM * DIM;

    k_init<<<(NUM_NODES + 255) / 256, 256, 0, stream>>>(
        mask ? mask : (unsigned char*)d_ws, Wih, Whh, WbIH, WbHH, have_mask ? 1 : 0);

    if (have_mask) {
        k_scatter<<<BATCH / 256, 256, 0, stream>>>(mask, idx);
        k_main<<<GRU_BLOCKS + COPY_BLOCKS, 512, 0, stream>>>(
            hidden, variance, idx, x, WbIH, WbHH, bih, bhh, mask, out0, out1, 0);
    } else {
        // fallback: copy-all, then gru overwrites updated rows
        k_main<<<COPY_BLOCKS, 512, 0, stream>>>(
            hidden, variance, idx, x, WbIH, WbHH, bih, bhh, nullptr, out0, out1, 1);
        k_main<<<GRU_BLOCKS, 512, 0, stream>>>(
            hidden, variance, idx, x, WbIH, WbHH, bih, bhh, nullptr, out0, out1, 2);
    }
}

// Round 4
// 293.154 us; speedup vs baseline: 3.7168x; 3.7168x over previous
//
#include <hip/hip_runtime.h>
#include <hip/hip_bf16.h>
#include <cstdint>
#include <cstddef>

#define NUM_NODES 500000
#define DIM 128
#define BATCH 131072

typedef __attribute__((ext_vector_type(8))) short short8;
typedef __attribute__((ext_vector_type(4))) short short4_t;
typedef __attribute__((ext_vector_type(4))) float f32x4;

static __device__ __forceinline__ short f2bf(float f) {
    unsigned u = __builtin_bit_cast(unsigned, f);
    u += 0x7fffu + ((u >> 16) & 1u);   // round-to-nearest-even
    return (short)(u >> 16);
}

// ---------------------------------------------------------------- init ----
__global__ void k_init(unsigned char* __restrict__ mask,
                       const float* __restrict__ Wih,
                       const float* __restrict__ Whh,
                       short* __restrict__ WbIH,
                       short* __restrict__ WbHH,
                       int do_mask) {
    int i = blockIdx.x * blockDim.x + threadIdx.x;
    if (do_mask && i < NUM_NODES) mask[i] = 0;
    if (i < 3 * DIM * DIM) {
        WbIH[i] = f2bf(Wih[i]);
        WbHH[i] = f2bf(Whh[i]);
    }
}

__global__ void k_scatter(unsigned char* __restrict__ mask, const int* __restrict__ idx) {
    int i = blockIdx.x * blockDim.x + threadIdx.x;
    if (i < BATCH) mask[idx[i]] = 1;
}

// ---------------------------------------------------------------- copy ----
// 256 thr, no LDS. thread -> 32B chunk of each plane (16 threads/row).
// grid: NUM_NODES*16/256 = 31250 blocks exactly.
__global__ void __launch_bounds__(256)
k_copy(const float* __restrict__ hidden,
       const float* __restrict__ variance,
       const unsigned char* __restrict__ mask,   // null -> copy all
       float* __restrict__ out0,
       float* __restrict__ out1) {
    int gid = blockIdx.x * 256 + threadIdx.x;
    int row = gid >> 4;
    int c8  = gid & 15;
    if (mask && mask[row]) return;               // gru writes this row
    size_t off = (size_t)row * DIM + c8 * 8;
    f32x4 a0 = *(const f32x4*)(hidden + off);
    f32x4 a1 = *(const f32x4*)(hidden + off + 4);
    f32x4 b0 = *(const f32x4*)(variance + off);
    f32x4 b1 = *(const f32x4*)(variance + off + 4);
    *(f32x4*)(out0 + off)     = a0;
    *(f32x4*)(out0 + off + 4) = a1;
    *(f32x4*)(out1 + off)     = b0;
    *(f32x4*)(out1 + off + 4) = b1;
}

// ----------------------------------------------------------------- gru ----
// 512 thr = 8 waves, 32 batch rows/block. wave w owns output dims 16w..16w+15
// for all three gate thirds -> gate combine is lane-local in MFMA C layout.
__global__ void __launch_bounds__(512)
k_gru(const float* __restrict__ hidden,
      const float* __restrict__ variance,
      const int*   __restrict__ idx,
      const float* __restrict__ xg,       // new_repr
      const short* __restrict__ WbIH,     // [384][128] bf16 bits
      const short* __restrict__ WbHH,
      const float* __restrict__ b_ih,
      const float* __restrict__ b_hh,
      float* __restrict__ out0,
      float* __restrict__ out1) {
    __shared__ __align__(16) char smem[34304];
    short (*Xb)[136] = (short(*)[136])smem;             // bf16 x tile
    short (*Hb)[136] = (short(*)[136])(smem + 8704);    // bf16 h tile
    float (*Hf)[132] = (float(*)[132])(smem + 17408);   // f32 h tile
    float (*Hn)[132] = (float(*)[132])smem;             // h_new, OVERLAYS Xb+Hb

    const int t  = threadIdx.x;
    const int rb = blockIdx.x * 32;

    // ---- stage x (f32->bf16) and gathered h (f32->bf16 + f32) ----
    for (int j = t; j < 1024; j += 512) {               // 1024 float4 chunks
        int row = j >> 5, c4 = j & 31;
        int node = idx[rb + row];
        f32x4 xv = *(const f32x4*)(xg + (size_t)(rb + row) * DIM + c4 * 4);
        f32x4 hv = *(const f32x4*)(hidden + (size_t)node * DIM + c4 * 4);
        short4_t xs, hs;
        xs.x = f2bf(xv.x); xs.y = f2bf(xv.y); xs.z = f2bf(xv.z); xs.w = f2bf(xv.w);
        hs.x = f2bf(hv.x); hs.y = f2bf(hv.y); hs.z = f2bf(hv.z); hs.w = f2bf(hv.w);
        *(short4_t*)&Xb[row][c4 * 4] = xs;
        *(short4_t*)&Hb[row][c4 * 4] = hs;
        *(f32x4*)&Hf[row][c4 * 4]    = hv;
    }
    __syncthreads();

    const int w  = t >> 6;       // wave id 0..7
    const int l  = t & 63;
    const int c  = l & 15;
    const int gq = l >> 4;

    f32x4 acc[2][3][2] = {};     // [m-tile][gate third][0=x@Wih 1=h@Whh]

    #pragma unroll
    for (int ks = 0; ks < 4; ++ks) {
        const int k0 = ks * 32 + gq * 8;
        short8 a[2][2];
        a[0][0] = *(const short8*)&Xb[c][k0];
        a[1][0] = *(const short8*)&Xb[16 + c][k0];
        a[0][1] = *(const short8*)&Hb[c][k0];
        a[1][1] = *(const short8*)&Hb[16 + c][k0];
        #pragma unroll
        for (int th = 0; th < 3; ++th) {
            const int o = w * 16 + th * 128 + c;        // gate output row of W
            const short8 bi = *(const short8*)(WbIH + (size_t)o * DIM + k0);
            const short8 bh = *(const short8*)(WbHH + (size_t)o * DIM + k0);
            #pragma unroll
            for (int mt = 0; mt < 2; ++mt) {
                acc[mt][th][0] = __builtin_amdgcn_mfma_f32_16x16x32_bf16(a[mt][0], bi, acc[mt][th][0], 0, 0, 0);
                acc[mt][th][1] = __builtin_amdgcn_mfma_f32_16x16x32_bf16(a[mt][1], bh, acc[mt][th][1], 0, 0, 0);
            }
        }
    }

    __syncthreads();   // Xb/Hb dead; safe to overlay with Hn

    // ---- gate math; lane holds (m = mt*16 + gq*4 + r, d = 16w + c) ----
    const int d = w * 16 + c;
    const float bs_r = b_ih[d]       + b_hh[d];
    const float bs_z = b_ih[d + 128] + b_hh[d + 128];
    const float bi_n = b_ih[d + 256];
    const float bh_n = b_hh[d + 256];

    #pragma unroll
    for (int mt = 0; mt < 2; ++mt) {
        #pragma unroll
        for (int r = 0; r < 4; ++r) {
            const int m = mt * 16 + gq * 4 + r;
            float s_r  = acc[mt][0][0][r] + acc[mt][0][1][r] + bs_r;
            float s_z  = acc[mt][1][0][r] + acc[mt][1][1][r] + bs_z;
            float gi_n = acc[mt][2][0][r] + bi_n;
            float gh_n = acc[mt][2][1][r] + bh_n;
            float rg = 1.f / (1.f + __expf(-s_r));
            float zg = 1.f / (1.f + __expf(-s_z));
            float aa = gi_n + rg * gh_n;
            float n  = 1.f - 2.f / (__expf(2.f * aa) + 1.f);   // tanh, inf-safe
            float h  = Hf[m][d];
            Hn[m][d] = (1.f - zg) * n + zg * h;
        }
    }
    __syncthreads();

    // ---- vectorized epilogue: coalesced variance read + both outputs ----
    for (int j = t; j < 1024; j += 512) {
        int row = j >> 5, c4 = j & 31;
        int node = idx[rb + row];                  // L1-hot re-read
        size_t off = (size_t)node * DIM + c4 * 4;
        f32x4 hn = *(f32x4*)&Hn[row][c4 * 4];
        f32x4 h  = *(f32x4*)&Hf[row][c4 * 4];
        f32x4 vv = *(const f32x4*)(variance + off);
        f32x4 var;
        var.x = 0.9f * vv.x + 0.1f * (hn.x - h.x) * (hn.x - h.x);
        var.y = 0.9f * vv.y + 0.1f * (hn.y - h.y) * (hn.y - h.y);
        var.z = 0.9f * vv.z + 0.1f * (hn.z - h.z) * (hn.z - h.z);
        var.w = 0.9f * vv.w + 0.1f * (hn.w - h.w) * (hn.w - h.w);
        *(f32x4*)(out0 + off) = hn;
        *(f32x4*)(out1 + off) = var;
    }
}

// -------------------------------------------------------------- launch ----
extern "C" void kernel_launch(void* const* d_in, const int* in_sizes, int n_in,
                              void* d_out, int out_size, void* d_ws, size_t ws_size,
                              hipStream_t stream) {
    const float* hidden   = (const float*)d_in[0];
    const float* variance = (const float*)d_in[1];
    const int*   idx      = (const int*)d_in[2];
    const float* x        = (const float*)d_in[3];
    const float* Wih      = (const float*)d_in[4];
    const float* Whh      = (const float*)d_in[5];
    const float* bih      = (const float*)d_in[6];
    const float* bhh      = (const float*)d_in[7];
    float* out0 = (float*)d_out;
    float* out1 = out0 + (size_t)NUM_NODES * DIM;

    const size_t maskBytes = (size_t)NUM_NODES;               // 1 byte per node
    const size_t wBytes    = (size_t)3 * DIM * DIM * 2;       // per matrix (bf16)
    const bool   have_mask = ws_size >= maskBytes + 16 + 2 * wBytes;

    unsigned char* mask = have_mask ? (unsigned char*)d_ws : nullptr;
    short* WbIH = have_mask ? (short*)((char*)d_ws + ((maskBytes + 15) & ~size_t(15)))
                            : (short*)d_ws;
    short* WbHH = WbIH + 3 * DIM * DIM;

    k_init<<<(NUM_NODES + 255) / 256, 256, 0, stream>>>(
        mask ? mask : (unsigned char*)d_ws, Wih, Whh, WbIH, WbHH, have_mask ? 1 : 0);

    if (have_mask)
        k_scatter<<<BATCH / 256, 256, 0, stream>>>(mask, idx);

    // copy non-updated rows (copy-all if no mask), then gru writes its rows
    k_copy<<<(NUM_NODES * 16) / 256, 256, 0, stream>>>(
        hidden, variance, mask, out0, out1);

    k_gru<<<BATCH / 32, 512, 0, stream>>>(hidden, variance, idx, x,
                                          WbIH, WbHH, bih, bhh, out0, out1);
}

// Round 5
// 288.638 us; speedup vs baseline: 3.7750x; 1.0156x over previous
//
#include <hip/hip_runtime.h>
#include <hip/hip_bf16.h>
#include <cstdint>
#include <cstddef>

#define NUM_NODES 500000
#define DIM 128
#define BATCH 131072

typedef __attribute__((ext_vector_type(8))) short short8;
typedef __attribute__((ext_vector_type(4))) short short4_t;
typedef __attribute__((ext_vector_type(4))) float f32x4;

static __device__ __forceinline__ short f2bf(float f) {
    unsigned u = __builtin_bit_cast(unsigned, f);
    u += 0x7fffu + ((u >> 16) & 1u);   // round-to-nearest-even
    return (short)(u >> 16);
}
static __device__ __forceinline__ float bf2f(short s) {
    unsigned u = ((unsigned)(unsigned short)s) << 16;
    return __builtin_bit_cast(float, u);
}

// ---------------------------------------------------------------- init ----
__global__ void k_init(unsigned char* __restrict__ mask,
                       const float* __restrict__ Wih,
                       const float* __restrict__ Whh,
                       short* __restrict__ WbIH,
                       short* __restrict__ WbHH,
                       int do_mask) {
    int i = blockIdx.x * blockDim.x + threadIdx.x;
    if (do_mask && i < NUM_NODES) mask[i] = 0;
    if (i < 3 * DIM * DIM) {
        WbIH[i] = f2bf(Wih[i]);
        WbHH[i] = f2bf(Whh[i]);
    }
}

__global__ void k_scatter(unsigned char* __restrict__ mask, const int* __restrict__ idx) {
    int i = blockIdx.x * blockDim.x + threadIdx.x;
    if (i < BATCH) mask[idx[i]] = 1;
}

// ---------------------------------------------------------------- copy ----
// UNCHANGED from round 4 (A/B isolation): 256 thr, no LDS, 16 thr/row, 32B/plane.
__global__ void __launch_bounds__(256)
k_copy(const float* __restrict__ hidden,
       const float* __restrict__ variance,
       const unsigned char* __restrict__ mask,   // null -> copy all
       float* __restrict__ out0,
       float* __restrict__ out1) {
    int gid = blockIdx.x * 256 + threadIdx.x;
    int row = gid >> 4;
    int c8  = gid & 15;
    if (mask && mask[row]) return;               // gru writes this row
    size_t off = (size_t)row * DIM + c8 * 8;
    f32x4 a0 = *(const f32x4*)(hidden + off);
    f32x4 a1 = *(const f32x4*)(hidden + off + 4);
    f32x4 b0 = *(const f32x4*)(variance + off);
    f32x4 b1 = *(const f32x4*)(variance + off + 4);
    *(f32x4*)(out0 + off)     = a0;
    *(f32x4*)(out0 + off + 4) = a1;
    *(f32x4*)(out1 + off)     = b0;
    *(f32x4*)(out1 + off + 4) = b1;
}

// ----------------------------------------------------------------- gru ----
// 512 thr = 8 waves, 32 batch rows/block. wave w owns output dims 16w..16w+15.
// v5 change: variance staged to LDS (bf16) in the stage phase -> epilogue has
// NO global loads (pure LDS read + store). LDS 43 KB -> 3 blocks/CU.
__global__ void __launch_bounds__(512)
k_gru(const float* __restrict__ hidden,
      const float* __restrict__ variance,
      const int*   __restrict__ idx,
      const float* __restrict__ xg,       // new_repr
      const short* __restrict__ WbIH,     // [384][128] bf16 bits
      const short* __restrict__ WbHH,
      const float* __restrict__ b_ih,
      const float* __restrict__ b_hh,
      float* __restrict__ out0,
      float* __restrict__ out1) {
    __shared__ __align__(16) char smem[43008];
    short (*Xb)[136] = (short(*)[136])smem;             // bf16 x tile
    short (*Hb)[136] = (short(*)[136])(smem + 8704);    // bf16 h tile
    short (*Vb)[136] = (short(*)[136])(smem + 17408);   // bf16 variance tile
    float (*Hf)[132] = (float(*)[132])(smem + 26112);   // f32 h tile
    float (*Hn)[132] = (float(*)[132])smem;             // h_new, OVERLAYS Xb+Hb

    const int t  = threadIdx.x;
    const int rb = blockIdx.x * 32;

    // ---- stage x, gathered h, gathered variance ----
    for (int j = t; j < 1024; j += 512) {               // 1024 float4 chunks
        int row = j >> 5, c4 = j & 31;
        int node = idx[rb + row];
        f32x4 xv = *(const f32x4*)(xg + (size_t)(rb + row) * DIM + c4 * 4);
        f32x4 hv = *(const f32x4*)(hidden + (size_t)node * DIM + c4 * 4);
        f32x4 vv = *(const f32x4*)(variance + (size_t)node * DIM + c4 * 4);
        short4_t xs, hs, vs;
        xs.x = f2bf(xv.x); xs.y = f2bf(xv.y); xs.z = f2bf(xv.z); xs.w = f2bf(xv.w);
        hs.x = f2bf(hv.x); hs.y = f2bf(hv.y); hs.z = f2bf(hv.z); hs.w = f2bf(hv.w);
        vs.x = f2bf(vv.x); vs.y = f2bf(vv.y); vs.z = f2bf(vv.z); vs.w = f2bf(vv.w);
        *(short4_t*)&Xb[row][c4 * 4] = xs;
        *(short4_t*)&Hb[row][c4 * 4] = hs;
        *(short4_t*)&Vb[row][c4 * 4] = vs;
        *(f32x4*)&Hf[row][c4 * 4]    = hv;
    }
    __syncthreads();

    const int w  = t >> 6;       // wave id 0..7
    const int l  = t & 63;
    const int c  = l & 15;
    const int gq = l >> 4;

    f32x4 acc[2][3][2] = {};     // [m-tile][gate third][0=x@Wih 1=h@Whh]

    #pragma unroll
    for (int ks = 0; ks < 4; ++ks) {
        const int k0 = ks * 32 + gq * 8;
        short8 a[2][2];
        a[0][0] = *(const short8*)&Xb[c][k0];
        a[1][0] = *(const short8*)&Xb[16 + c][k0];
        a[0][1] = *(const short8*)&Hb[c][k0];
        a[1][1] = *(const short8*)&Hb[16 + c][k0];
        #pragma unroll
        for (int th = 0; th < 3; ++th) {
            const int o = w * 16 + th * 128 + c;        // gate output row of W
            const short8 bi = *(const short8*)(WbIH + (size_t)o * DIM + k0);
            const short8 bh = *(const short8*)(WbHH + (size_t)o * DIM + k0);
            #pragma unroll
            for (int mt = 0; mt < 2; ++mt) {
                acc[mt][th][0] = __builtin_amdgcn_mfma_f32_16x16x32_bf16(a[mt][0], bi, acc[mt][th][0], 0, 0, 0);
                acc[mt][th][1] = __builtin_amdgcn_mfma_f32_16x16x32_bf16(a[mt][1], bh, acc[mt][th][1], 0, 0, 0);
            }
        }
    }

    __syncthreads();   // Xb/Hb dead; safe to overlay with Hn

    // ---- gate math; lane holds (m = mt*16 + gq*4 + r, d = 16w + c) ----
    const int d = w * 16 + c;
    const float bs_r = b_ih[d]       + b_hh[d];
    const float bs_z = b_ih[d + 128] + b_hh[d + 128];
    const float bi_n = b_ih[d + 256];
    const float bh_n = b_hh[d + 256];

    #pragma unroll
    for (int mt = 0; mt < 2; ++mt) {
        #pragma unroll
        for (int r = 0; r < 4; ++r) {
            const int m = mt * 16 + gq * 4 + r;
            float s_r  = acc[mt][0][0][r] + acc[mt][0][1][r] + bs_r;
            float s_z  = acc[mt][1][0][r] + acc[mt][1][1][r] + bs_z;
            float gi_n = acc[mt][2][0][r] + bi_n;
            float gh_n = acc[mt][2][1][r] + bh_n;
            float rg = 1.f / (1.f + __expf(-s_r));
            float zg = 1.f / (1.f + __expf(-s_z));
            float aa = gi_n + rg * gh_n;
            float n  = 1.f - 2.f / (__expf(2.f * aa) + 1.f);   // tanh, inf-safe
            float h  = Hf[m][d];
            Hn[m][d] = (1.f - zg) * n + zg * h;
        }
    }
    __syncthreads();

    // ---- epilogue: pure LDS reads + coalesced stores (no global loads) ----
    for (int j = t; j < 1024; j += 512) {
        int row = j >> 5, c4 = j & 31;
        int node = idx[rb + row];                  // L1-hot re-read
        size_t off = (size_t)node * DIM + c4 * 4;
        f32x4 hn = *(f32x4*)&Hn[row][c4 * 4];
        f32x4 h  = *(f32x4*)&Hf[row][c4 * 4];
        short4_t vs = *(short4_t*)&Vb[row][c4 * 4];
        f32x4 var;
        var.x = 0.9f * bf2f(vs.x) + 0.1f * (hn.x - h.x) * (hn.x - h.x);
        var.y = 0.9f * bf2f(vs.y) + 0.1f * (hn.y - h.y) * (hn.y - h.y);
        var.z = 0.9f * bf2f(vs.z) + 0.1f * (hn.z - h.z) * (hn.z - h.z);
        var.w = 0.9f * bf2f(vs.w) + 0.1f * (hn.w - h.w) * (hn.w - h.w);
        *(f32x4*)(out0 + off) = hn;
        *(f32x4*)(out1 + off) = var;
    }
}

// -------------------------------------------------------------- launch ----
extern "C" void kernel_launch(void* const* d_in, const int* in_sizes, int n_in,
                              void* d_out, int out_size, void* d_ws, size_t ws_size,
                              hipStream_t stream) {
    const float* hidden   = (const float*)d_in[0];
    const float* variance = (const float*)d_in[1];
    const int*   idx      = (const int*)d_in[2];
    const float* x        = (const float*)d_in[3];
    const float* Wih      = (const float*)d_in[4];
    const float* Whh      = (const float*)d_in[5];
    const float* bih      = (const float*)d_in[6];
    const float* bhh      = (const float*)d_in[7];
    float* out0 = (float*)d_out;
    float* out1 = out0 + (size_t)NUM_NODES * DIM;

    const size_t maskBytes = (size_t)NUM_NODES;               // 1 byte per node
    const size_t wBytes    = (size_t)3 * DIM * DIM * 2;       // per matrix (bf16)
    const bool   have_mask = ws_size >= maskBytes + 16 + 2 * wBytes;

    unsigned char* mask = have_mask ? (unsigned char*)d_ws : nullptr;
    short* WbIH = have_mask ? (short*)((char*)d_ws + ((maskBytes + 15) & ~size_t(15)))
                            : (short*)d_ws;
    short* WbHH = WbIH + 3 * DIM * DIM;

    k_init<<<(NUM_NODES + 255) / 256, 256, 0, stream>>>(
        mask ? mask : (unsigned char*)d_ws, Wih, Whh, WbIH, WbHH, have_mask ? 1 : 0);

    if (have_mask)
        k_scatter<<<BATCH / 256, 256, 0, stream>>>(mask, idx);

    // copy non-updated rows (copy-all if no mask), then gru writes its rows
    k_copy<<<(NUM_NODES * 16) / 256, 256, 0, stream>>>(
        hidden, variance, mask, out0, out1);

    k_gru<<<BATCH / 32, 512, 0, stream>>>(hidden, variance, idx, x,
                                          WbIH, WbHH, bih, bhh, out0, out1);
}